// Round 1
// 811.339 us; speedup vs baseline: 1.2471x; 1.2471x over previous
//
#include <hip/hip_runtime.h>
#include <math.h>

// Problem constants (fixed by reference)
#define NS 128       // scalar channels
#define TD 480       // total dim per row
#define NF 224       // gate channels (128 scalar + 96 vector)
#define BN 112       // bottleneck dim
#define TM 64        // rows per block
#define K1 224       // GEMM1 K
#define K1S 232      // gate_A / W1T stride (bf16 elems; 464B = 16B-aligned, bank-friendly)
#define K2S 136      // h_A / W2T stride (K padded 112->128, +8 pad; 272B)
#define GS 225       // gates f32 stride (breaks 4-quad bank collision)
#define W1T_ELEMS (BN * K1S)   // 25984 bf16
#define W2T_ELEMS (NF * K2S)   // 30464 bf16

typedef __bf16 bf16x8 __attribute__((ext_vector_type(8)));
typedef float f32x4 __attribute__((ext_vector_type(4)));

__device__ __forceinline__ unsigned short f2bf(float f) {
  union { float f; unsigned u; } v; v.f = f;
  unsigned r = v.u + 0x7FFFu + ((v.u >> 16) & 1u);   // RTNE
  return (unsigned short)(r >> 16);
}

// Wave-local region (each wave touches only its own 16-row band before the
// first barrier), aliased by the post-GEMM2 gates tile.
struct SMemA {
  unsigned short gateA[TM * K1S];  // 29696 B  (A operand, GEMM1)
  unsigned short hA[TM * K2S];     // 17408 B  (A operand, GEMM2; k in [112,128) zeroed)
  float rowbuf[4][352];            //  5632 B  (per-wave squared vector entries)
};
struct __align__(16) SMem {
  union {
    SMemA a;                       // 52736 B
    float gates[TM * GS];          // 57600 B (written after barrier #1)
  };
  float absb[NS];                  // 512 B  (affine_bias, survives to phase 3)
  float meanv[TM];                 // 256 B
};
// total: 58368 B -> 2 blocks/CU (was 116736 B -> 1 block/CU)

__global__ void prep_kernel(const float* __restrict__ W1, const float* __restrict__ W2,
                            unsigned short* __restrict__ w1t, unsigned short* __restrict__ w2t) {
  int t = blockIdx.x * 256 + threadIdx.x;
  if (t < W1T_ELEMS) {
    int n = t / K1S, k = t - n * K1S;
    float v = (k < K1) ? W1[k * BN + n] : 0.0f;   // W1 is (224,112) row-major -> W1T[n][k]
    w1t[t] = f2bf(v);
  } else {
    int t2 = t - W1T_ELEMS;
    if (t2 < W2T_ELEMS) {
      int n = t2 / K2S, k = t2 - n * K2S;
      float v = (k < BN) ? W2[k * NF + n] : 0.0f; // W2 is (112,224) -> W2T[n][k], k-pad zeroed
      w2t[t2] = f2bf(v);
    }
  }
}

__global__ __launch_bounds__(256, 2) void fused_kernel(
    const float* __restrict__ X,
    const float* __restrict__ b1, const float* __restrict__ b2,
    const float* __restrict__ aw, const float* __restrict__ ab,
    const unsigned short* __restrict__ w1t, const unsigned short* __restrict__ w2t,
    float* __restrict__ OUT) {
  __shared__ SMem sm;
  const int tid  = threadIdx.x;
  const int lane = tid & 63;
  const int w    = tid >> 6;
  const int l15  = lane & 15;
  const int quad = lane >> 4;
  const int R0   = blockIdx.x * TM;

  // ---- stage affine_bias (wave-split; visible after barrier #2) ----
  if (lane < 32) sm.absb[32 * w + lane] = ab[32 * w + lane];

  // ---- zero hA K-pad [112,128) for this wave's own 16-row band ----
  if (lane < 32) {
    int r = 16 * w + (lane >> 1);
    *(f32x4*)&sm.a.hA[r * K2S + 112 + 8 * (lane & 1)] = (f32x4){0.f, 0.f, 0.f, 0.f};
  }

  // ---- phase 1: per-row stats + gate_in (wave w owns rows [16w,16w+16)) ----
  // dwordx4 loads: lane<32 of v0 = scalars (cols 4l..4l+3); lane>=32 of v0 and
  // lane<56 of v1 = vector entries.
  {
    f32x4 cur0, cur1, nxt0, nxt1;
    const int rbase = 16 * w;
    auto loadRow = [&](int rl, f32x4& a0, f32x4& a1) {
      const float* rp = X + (size_t)(R0 + rl) * TD;
      a0 = *(const f32x4*)(rp + 4 * lane);
      if (lane < 56) a1 = *(const f32x4*)(rp + 256 + 4 * lane);
    };
    auto procRow = [&](int rl, f32x4 v0, f32x4 v1) {
      float ssum = (lane < 32) ? (v0[0] + v0[1] + v0[2] + v0[3]) : 0.0f;
      #pragma unroll
      for (int m = 32; m >= 1; m >>= 1) ssum += __shfl_xor(ssum, m, 64);
      float mean = ssum * (1.0f / 128.0f);
      float* rb = sm.a.rowbuf[w];
      if (lane >= 32) {                              // cols 128..255 -> idx 0..127
        f32x4 sq;
        #pragma unroll
        for (int j = 0; j < 4; ++j) sq[j] = v0[j] * v0[j];
        *(f32x4*)&rb[4 * (lane - 32)] = sq;
      }
      if (lane < 56) {                               // cols 256..479 -> idx 128..351
        f32x4 sq;
        #pragma unroll
        for (int j = 0; j < 4; ++j) sq[j] = v1[j] * v1[j];
        *(f32x4*)&rb[128 + 4 * lane] = sq;
      }
      __builtin_amdgcn_wave_barrier();               // same-wave DS in-order; block reordering
      float s3 = rb[3 * lane] + rb[3 * lane + 1] + rb[3 * lane + 2];
      float r3 = sqrtf(s3 * (1.0f / 3.0f) + 1e-6f);
      unsigned short* ga = &sm.a.gateA[rl * K1S];
      if (lane < 32) {                               // centered scalars, packed 4-wide
        ushort4 pk;
        pk.x = f2bf(v0[0] - mean); pk.y = f2bf(v0[1] - mean);
        pk.z = f2bf(v0[2] - mean); pk.w = f2bf(v0[3] - mean);
        *(ushort4*)&ga[4 * lane] = pk;
      }
      ga[128 + lane] = f2bf(r3);                     // 3-dim RMS, ch 0..63
      if (lane < 32) {                               // 5-dim RMS, ch 64..95
        float s5 = 0.0f;
        #pragma unroll
        for (int q = 0; q < 5; ++q) s5 += rb[192 + 5 * lane + q];
        ga[192 + lane] = f2bf(sqrtf(s5 * 0.2f + 1e-6f));
      }
      if (lane == 0) sm.meanv[rl] = mean;
      __builtin_amdgcn_wave_barrier();
    };
    loadRow(rbase, cur0, cur1);
    #pragma unroll
    for (int i = 0; i < 16; ++i) {                   // SW pipeline: prefetch row i+1
      if (i < 15) loadRow(rbase + i + 1, nxt0, nxt1);
      procRow(rbase + i, cur0, cur1);
      cur0 = nxt0; cur1 = nxt1;
    }
  }
  // NO __syncthreads: phase1 -> GEMM1 -> GEMM2 is wave-local; waves run decoupled.

  // ---- GEMM1: h = silu(gate_in @ W1 + b1); B fragments direct from global (L2-hot) ----
  {
    f32x4 acc[7];
    #pragma unroll
    for (int j = 0; j < 7; ++j) acc[j] = (f32x4){0.f, 0.f, 0.f, 0.f};
    const unsigned short* gA = &sm.a.gateA[(16 * w + l15) * K1S];
    const unsigned short* B1p = w1t + l15 * K1S + quad * 8;
    #pragma unroll
    for (int kk = 0; kk < 7; ++kk) {
      bf16x8 a = *(const bf16x8*)(gA + kk * 32 + quad * 8);
      #pragma unroll
      for (int nb = 0; nb < 7; ++nb) {
        bf16x8 bb = *(const bf16x8*)(B1p + nb * 16 * K1S + kk * 32);
        acc[nb] = __builtin_amdgcn_mfma_f32_16x16x32_bf16(a, bb, acc[nb], 0, 0, 0);
      }
    }
    #pragma unroll
    for (int nb = 0; nb < 7; ++nb) {
      int n = nb * 16 + l15;
      float bias = b1[n];                            // tiny, L1-hot across blocks
      #pragma unroll
      for (int i = 0; i < 4; ++i) {
        int r = 16 * w + quad * 4 + i;               // C layout: col=lane&15, row=quad*4+i
        float hv = acc[nb][i] + bias;
        float sg = 1.0f / (1.0f + __expf(-hv));
        sm.a.hA[r * K2S + n] = f2bf(hv * sg);
      }
    }
  }

  // ---- GEMM2: gates = 2*sigmoid(h @ W2 + b2) * affine_weight; B direct from global ----
  float garr[56];
  {
    f32x4 acc[14];
    #pragma unroll
    for (int j = 0; j < 14; ++j) acc[j] = (f32x4){0.f, 0.f, 0.f, 0.f};
    const unsigned short* hAp = &sm.a.hA[(16 * w + l15) * K2S];
    const unsigned short* B2p = w2t + l15 * K2S + quad * 8;
    #pragma unroll
    for (int kk = 0; kk < 4; ++kk) {
      bf16x8 a = *(const bf16x8*)(hAp + kk * 32 + quad * 8);
      #pragma unroll
      for (int nb = 0; nb < 14; ++nb) {
        bf16x8 bb = *(const bf16x8*)(B2p + nb * 16 * K2S + kk * 32);
        acc[nb] = __builtin_amdgcn_mfma_f32_16x16x32_bf16(a, bb, acc[nb], 0, 0, 0);
      }
    }
    #pragma unroll
    for (int nb = 0; nb < 14; ++nb) {
      int n = nb * 16 + l15;
      float b2v = b2[n], awv = aw[n];
      #pragma unroll
      for (int i = 0; i < 4; ++i) {
        float z = acc[nb][i] + b2v;
        garr[nb * 4 + i] = 2.0f * awv / (1.0f + __expf(-z));
      }
    }
  }

  __syncthreads();                                   // #1: all waves done with gateA/hA/rowbuf
  #pragma unroll
  for (int nb = 0; nb < 14; ++nb) {
    #pragma unroll
    for (int i = 0; i < 4; ++i) {
      int r = 16 * w + quad * 4 + i;
      sm.gates[r * GS + nb * 16 + l15] = garr[nb * 4 + i];
    }
  }
  __syncthreads();                                   // #2: gates tile ready

  // ---- phase 3: coalesced re-read of x (L2-warm), scale, store ----
  const float* Xb = X + (size_t)R0 * TD;
  float* Ob = OUT + (size_t)R0 * TD;
  #pragma unroll 5
  for (int it = 0; it < 30; ++it) {                  // 64*480/4 / 256 = 30 exactly
    int u = tid + it * 256;
    int e = u * 4;
    int r = e / TD;
    int c = e - r * TD;                              // float4 never crosses a row (480%4==0)
    f32x4 xv = *(const f32x4*)(Xb + e);
    float m = sm.meanv[r];
    float out[4];
    #pragma unroll
    for (int i = 0; i < 4; ++i) {
      int ci = c + i;
      int ch = (ci < NS) ? ci
             : ((ci < 320) ? (NS + (ci - NS) / 3) : (192 + (ci - 320) / 5));
      float g = sm.gates[r * GS + ch];
      out[i] = (ci < NS) ? ((xv[i] - m) * g + sm.absb[ci]) : (xv[i] * g);
    }
    f32x4 ov = {out[0], out[1], out[2], out[3]};
    __builtin_nontemporal_store(ov, (f32x4*)(Ob + e));  // don't evict X we re-read
  }
}

extern "C" void kernel_launch(void* const* d_in, const int* in_sizes, int n_in,
                              void* d_out, int out_size, void* d_ws, size_t ws_size,
                              hipStream_t stream) {
  const float* X  = (const float*)d_in[0];
  const float* W1 = (const float*)d_in[1];
  const float* b1 = (const float*)d_in[2];
  const float* W2 = (const float*)d_in[3];
  const float* b2 = (const float*)d_in[4];
  const float* aw = (const float*)d_in[5];
  const float* ab = (const float*)d_in[6];
  float* OUT = (float*)d_out;
  unsigned short* w1t = (unsigned short*)d_ws;
  unsigned short* w2t = w1t + W1T_ELEMS;              // ~113 KB of d_ws total

  int n = in_sizes[0] / TD;                           // 200000 (divisible by TM=64)
  int pb = (W1T_ELEMS + W2T_ELEMS + 255) / 256;
  hipLaunchKernelGGL(prep_kernel, dim3(pb), dim3(256), 0, stream, W1, W2, w1t, w2t);
  hipLaunchKernelGGL(fused_kernel, dim3(n / TM), dim3(256), 0, stream,
                     X, b1, b2, aw, ab, w1t, w2t, OUT);
}

// Round 2
// 765.079 us; speedup vs baseline: 1.3225x; 1.0605x over previous
//
#include <hip/hip_runtime.h>
#include <math.h>

// Problem constants (fixed by reference)
#define NS 128       // scalar channels
#define TD 480       // total dim per row
#define NF 224       // gate channels (128 scalar + 96 vector)
#define BN 112       // bottleneck dim
#define TM 64        // rows per block
#define K1 224       // GEMM1 K
#define K1S 232      // gate_A / W1T stride (bf16 elems; 464B = 16B-aligned, bank-friendly)
#define K2S 136      // h_A / W2T stride (K padded 112->128, +8 pad; 272B)
#define GS 225       // gates f32 stride (breaks 4-quad bank collision)
#define W1T_ELEMS (BN * K1S)   // 25984 bf16
#define W2T_ELEMS (NF * K2S)   // 30464 bf16

typedef __bf16 bf16x8 __attribute__((ext_vector_type(8)));
typedef float f32x4 __attribute__((ext_vector_type(4)));

__device__ __forceinline__ unsigned short f2bf(float f) {
  union { float f; unsigned u; } v; v.f = f;
  unsigned r = v.u + 0x7FFFu + ((v.u >> 16) & 1u);   // RTNE
  return (unsigned short)(r >> 16);
}

// Wave-local region (each wave touches only its own 16-row band before the
// first barrier). The post-GEMM2 gates tile is HALVED to 32 rows (28800 B)
// so it nests inside gateA (29696 B) -> union costs nothing -> 3 blocks/CU.
struct SMemA {
  unsigned short gateA[TM * K1S];  // 29696 B  (A operand, GEMM1)
  unsigned short hA[TM * K2S];     // 17408 B  (A operand, GEMM2; k in [112,128) zeroed)
  float rowbuf[4][352];            //  5632 B  (per-wave squared vector entries)
};
struct __align__(16) SMem {
  union {
    SMemA a;                       // 52736 B
    float gates[32 * GS];          // 28800 B (32-row half-tile, written after barrier #1)
  };
  float absb[NS];                  // 512 B  (affine_bias, survives to phase 3)
  float meanv[TM];                 // 256 B
};
// total: 53504 B -> 3 blocks/CU (was 58368 B -> 2 blocks/CU)

__global__ void prep_kernel(const float* __restrict__ W1, const float* __restrict__ W2,
                            unsigned short* __restrict__ w1t, unsigned short* __restrict__ w2t) {
  int t = blockIdx.x * 256 + threadIdx.x;
  if (t < W1T_ELEMS) {
    int n = t / K1S, k = t - n * K1S;
    float v = (k < K1) ? W1[k * BN + n] : 0.0f;   // W1 is (224,112) row-major -> W1T[n][k]
    w1t[t] = f2bf(v);
  } else {
    int t2 = t - W1T_ELEMS;
    if (t2 < W2T_ELEMS) {
      int n = t2 / K2S, k = t2 - n * K2S;
      float v = (k < BN) ? W2[k * NF + n] : 0.0f; // W2 is (112,224) -> W2T[n][k], k-pad zeroed
      w2t[t2] = f2bf(v);
    }
  }
}

__global__ __launch_bounds__(256, 3) void fused_kernel(
    const float* __restrict__ X,
    const float* __restrict__ b1, const float* __restrict__ b2,
    const float* __restrict__ aw, const float* __restrict__ ab,
    const unsigned short* __restrict__ w1t, const unsigned short* __restrict__ w2t,
    float* __restrict__ OUT) {
  __shared__ SMem sm;
  const int tid  = threadIdx.x;
  const int lane = tid & 63;
  const int w    = tid >> 6;
  const int l15  = lane & 15;
  const int quad = lane >> 4;
  const int R0   = blockIdx.x * TM;

  // ---- stage affine_bias (wave-split; visible after barrier #2) ----
  if (lane < 32) sm.absb[32 * w + lane] = ab[32 * w + lane];

  // ---- zero hA K-pad [112,128) for this wave's own 16-row band ----
  if (lane < 32) {
    int r = 16 * w + (lane >> 1);
    *(f32x4*)&sm.a.hA[r * K2S + 112 + 8 * (lane & 1)] = (f32x4){0.f, 0.f, 0.f, 0.f};
  }

  // ---- phase 1: per-row stats + gate_in (wave w owns rows [16w,16w+16)) ----
  // dwordx4 loads; 2-deep row prefetch (3 rows in flight ~ 6 KB/wave of MLP).
  {
    f32x4 a0, a1, bb0, bb1, c0, c1;
    const int rbase = 16 * w;
    auto loadRow = [&](int rl, f32x4& v0, f32x4& v1) {
      const float* rp = X + (size_t)(R0 + rl) * TD;
      v0 = *(const f32x4*)(rp + 4 * lane);
      if (lane < 56) v1 = *(const f32x4*)(rp + 256 + 4 * lane);
    };
    auto procRow = [&](int rl, f32x4 v0, f32x4 v1) {
      float ssum = (lane < 32) ? (v0[0] + v0[1] + v0[2] + v0[3]) : 0.0f;
      #pragma unroll
      for (int m = 32; m >= 1; m >>= 1) ssum += __shfl_xor(ssum, m, 64);
      float mean = ssum * (1.0f / 128.0f);
      float* rb = sm.a.rowbuf[w];
      if (lane >= 32) {                              // cols 128..255 -> idx 0..127
        f32x4 sq;
        #pragma unroll
        for (int j = 0; j < 4; ++j) sq[j] = v0[j] * v0[j];
        *(f32x4*)&rb[4 * (lane - 32)] = sq;
      }
      if (lane < 56) {                               // cols 256..479 -> idx 128..351
        f32x4 sq;
        #pragma unroll
        for (int j = 0; j < 4; ++j) sq[j] = v1[j] * v1[j];
        *(f32x4*)&rb[128 + 4 * lane] = sq;
      }
      __builtin_amdgcn_wave_barrier();               // same-wave DS in-order; block reordering
      float s3 = rb[3 * lane] + rb[3 * lane + 1] + rb[3 * lane + 2];
      float r3 = sqrtf(s3 * (1.0f / 3.0f) + 1e-6f);
      unsigned short* ga = &sm.a.gateA[rl * K1S];
      if (lane < 32) {                               // centered scalars, packed 4-wide
        ushort4 pk;
        pk.x = f2bf(v0[0] - mean); pk.y = f2bf(v0[1] - mean);
        pk.z = f2bf(v0[2] - mean); pk.w = f2bf(v0[3] - mean);
        *(ushort4*)&ga[4 * lane] = pk;
      }
      ga[128 + lane] = f2bf(r3);                     // 3-dim RMS, ch 0..63
      if (lane < 32) {                               // 5-dim RMS, ch 64..95
        float s5 = 0.0f;
        #pragma unroll
        for (int q = 0; q < 5; ++q) s5 += rb[192 + 5 * lane + q];
        ga[192 + lane] = f2bf(sqrtf(s5 * 0.2f + 1e-6f));
      }
      if (lane == 0) sm.meanv[rl] = mean;
      __builtin_amdgcn_wave_barrier();
    };
    loadRow(rbase, a0, a1);
    loadRow(rbase + 1, bb0, bb1);
    #pragma unroll
    for (int i = 0; i < 16; ++i) {                   // SW pipeline, depth 2
      if (i < 14) loadRow(rbase + i + 2, c0, c1);
      procRow(rbase + i, a0, a1);
      a0 = bb0; a1 = bb1; bb0 = c0; bb1 = c1;
    }
  }
  // NO __syncthreads: phase1 -> GEMM1 -> GEMM2 is wave-local; waves run decoupled.

  // ---- GEMM1: h = silu(gate_in @ W1 + b1); B fragments direct from global (L2-hot) ----
  {
    f32x4 acc[7];
    #pragma unroll
    for (int j = 0; j < 7; ++j) acc[j] = (f32x4){0.f, 0.f, 0.f, 0.f};
    const unsigned short* gA = &sm.a.gateA[(16 * w + l15) * K1S];
    const unsigned short* B1p = w1t + l15 * K1S + quad * 8;
    #pragma unroll
    for (int kk = 0; kk < 7; ++kk) {
      bf16x8 a = *(const bf16x8*)(gA + kk * 32 + quad * 8);
      #pragma unroll
      for (int nb = 0; nb < 7; ++nb) {
        bf16x8 bb = *(const bf16x8*)(B1p + nb * 16 * K1S + kk * 32);
        acc[nb] = __builtin_amdgcn_mfma_f32_16x16x32_bf16(a, bb, acc[nb], 0, 0, 0);
      }
    }
    #pragma unroll
    for (int nb = 0; nb < 7; ++nb) {
      int n = nb * 16 + l15;
      float bias = b1[n];                            // tiny, L1-hot across blocks
      #pragma unroll
      for (int i = 0; i < 4; ++i) {
        int r = 16 * w + quad * 4 + i;               // C layout: col=lane&15, row=quad*4+i
        float hv = acc[nb][i] + bias;
        float sg = 1.0f / (1.0f + __expf(-hv));
        sm.a.hA[r * K2S + n] = f2bf(hv * sg);
      }
    }
  }

  // ---- GEMM2: gates = 2*sigmoid(h @ W2 + b2) * affine_weight; B direct from global ----
  float garr[56];
  {
    f32x4 acc[14];
    #pragma unroll
    for (int j = 0; j < 14; ++j) acc[j] = (f32x4){0.f, 0.f, 0.f, 0.f};
    const unsigned short* hAp = &sm.a.hA[(16 * w + l15) * K2S];
    const unsigned short* B2p = w2t + l15 * K2S + quad * 8;
    #pragma unroll
    for (int kk = 0; kk < 4; ++kk) {
      bf16x8 a = *(const bf16x8*)(hAp + kk * 32 + quad * 8);
      #pragma unroll
      for (int nb = 0; nb < 14; ++nb) {
        bf16x8 bb = *(const bf16x8*)(B2p + nb * 16 * K2S + kk * 32);
        acc[nb] = __builtin_amdgcn_mfma_f32_16x16x32_bf16(a, bb, acc[nb], 0, 0, 0);
      }
    }
    #pragma unroll
    for (int nb = 0; nb < 14; ++nb) {
      int n = nb * 16 + l15;
      float b2v = b2[n], awv = aw[n];
      #pragma unroll
      for (int i = 0; i < 4; ++i) {
        float z = acc[nb][i] + b2v;
        garr[nb * 4 + i] = 2.0f * awv / (1.0f + __expf(-z));
      }
    }
  }

  // ---- phase 3: two 32-row halves; gates half-tile aliases gateA ----
  const float* Xb = X + (size_t)R0 * TD;
  float* Ob = OUT + (size_t)R0 * TD;

  // wave pair (w>>1)==h owns half h: local row = 16*(w&1)+quad*4+i
  auto writeGates = [&]() {
    int rl = 16 * (w & 1) + quad * 4;
    #pragma unroll
    for (int nb = 0; nb < 14; ++nb) {
      #pragma unroll
      for (int i = 0; i < 4; ++i)
        sm.gates[(rl + i) * GS + nb * 16 + l15] = garr[nb * 4 + i];
    }
  };

  f32x4 pre[5];
  auto preload = [&](const float* Xh) {
    #pragma unroll
    for (int it = 0; it < 5; ++it)
      pre[it] = __builtin_nontemporal_load((const f32x4*)(Xh + 4 * (tid + it * 256)));
  };
  auto doHalf = [&](int h, const float* Xh, float* Oh) {
    const int roff = h * 32;
    auto proc = [&](f32x4 xv, int u) {
      int e = u * 4;
      int r = e / TD;
      int c = e - r * TD;                            // float4 never crosses a row (480%4==0)
      float m = sm.meanv[r + roff];
      float out[4];
      #pragma unroll
      for (int i = 0; i < 4; ++i) {
        int ci = c + i;
        int ch = (ci < NS) ? ci
               : ((ci < 320) ? (NS + (ci - NS) / 3) : (192 + (ci - 320) / 5));
        float g = sm.gates[r * GS + ch];
        out[i] = (ci < NS) ? ((xv[i] - m) * g + sm.absb[ci]) : (xv[i] * g);
      }
      f32x4 ov = {out[0], out[1], out[2], out[3]};
      __builtin_nontemporal_store(ov, (f32x4*)(Oh + e));  // dead after write
    };
    #pragma unroll
    for (int it = 0; it < 5; ++it) proc(pre[it], tid + it * 256);
    #pragma unroll 5
    for (int it = 5; it < 15; ++it) {
      int u = tid + it * 256;
      f32x4 xv = __builtin_nontemporal_load((const f32x4*)(Xh + 4 * u));
      proc(xv, u);
    }
  };

  preload(Xb);                                       // half-1 X: L2-hot, hides barriers
  __syncthreads();                                   // #1: all waves done with gateA/hA/rowbuf
  if ((w >> 1) == 0) writeGates();
  __syncthreads();                                   // #2: gates rows 0..31 ready
  doHalf(0, Xb, Ob);
  preload(Xb + 32 * TD);                             // half-2 X, issued before barrier #3
  __syncthreads();                                   // #3: all waves done reading half-1 gates
  if ((w >> 1) == 1) writeGates();
  __syncthreads();                                   // #4: gates rows 32..63 ready
  doHalf(1, Xb + 32 * TD, Ob + 32 * TD);
}

extern "C" void kernel_launch(void* const* d_in, const int* in_sizes, int n_in,
                              void* d_out, int out_size, void* d_ws, size_t ws_size,
                              hipStream_t stream) {
  const float* X  = (const float*)d_in[0];
  const float* W1 = (const float*)d_in[1];
  const float* b1 = (const float*)d_in[2];
  const float* W2 = (const float*)d_in[3];
  const float* b2 = (const float*)d_in[4];
  const float* aw = (const float*)d_in[5];
  const float* ab = (const float*)d_in[6];
  float* OUT = (float*)d_out;
  unsigned short* w1t = (unsigned short*)d_ws;
  unsigned short* w2t = w1t + W1T_ELEMS;              // ~113 KB of d_ws total

  int n = in_sizes[0] / TD;                           // 200000 (divisible by TM=64)
  int pb = (W1T_ELEMS + W2T_ELEMS + 255) / 256;
  hipLaunchKernelGGL(prep_kernel, dim3(pb), dim3(256), 0, stream, W1, W2, w1t, w2t);
  hipLaunchKernelGGL(fused_kernel, dim3(n / TM), dim3(256), 0, stream,
                     X, b1, b2, aw, ab, w1t, w2t, OUT);
}